// Round 15
// baseline (120.899 us; speedup 1.0000x reference)
//
#include <hip/hip_runtime.h>
#include <cmath>

// Problem constants
#define B_    16
#define N_    1024
#define NHID_ 32
#define NHEAD_ 4
#define NPRED_ 12
#define ALPHA 0.2f
#define LOG2E 1.442695041f

typedef __attribute__((ext_vector_type(8)))  short          short8;
typedef __attribute__((ext_vector_type(4)))  float          floatx4;
typedef __attribute__((ext_vector_type(2)))  float          float2v;
typedef __attribute__((ext_vector_type(4)))  unsigned       uintx4;
typedef __attribute__((ext_vector_type(4)))  unsigned short ushort4v;
typedef __attribute__((ext_vector_type(8)))  unsigned short ushort8v;

// bf16 bit-pattern helpers
__device__ __forceinline__ float bs2f(unsigned short s) {
    return __uint_as_float(((unsigned)s) << 16);
}
__device__ __forceinline__ short f2bs(float f) {
    unsigned u = __float_as_uint(f);
    unsigned r = (u + 0x7fffu + ((u >> 16) & 1u)) >> 16;  // RNE
    return (short)r;
}
__device__ __forceinline__ float ldin(const void* p, long i, int isbf) {
    if (isbf) return bs2f(((const unsigned short*)p)[i]);
    return ((const float*)p)[i];
}
__device__ __forceinline__ float fexp2(float x) {
#if __has_builtin(__builtin_amdgcn_exp2f)
    return __builtin_amdgcn_exp2f(x);
#else
    return __expf(x * 0.6931471805599453f);
#endif
}
// pack high halves of two fp32 into bf16x2 (truncation / RTZ)
__device__ __forceinline__ unsigned pk2t(unsigned u0, unsigned u1) {
#if __has_builtin(__builtin_amdgcn_perm)
    return __builtin_amdgcn_perm(u1, u0, 0x07060302u);
#else
    return (u0 >> 16) | (u1 & 0xffff0000u);
#endif
}
__device__ __forceinline__ float2v vmax2(float2v a, float2v b) {
#if __has_builtin(__builtin_elementwise_max)
    return __builtin_elementwise_max(a, b);
#else
    float2v r; r.x = fmaxf(a.x, b.x); r.y = fmaxf(a.y, b.y); return r;
#endif
}
__device__ __forceinline__ float2v vfma2(float2v a, float2v b, float2v c) {
#if __has_builtin(__builtin_elementwise_fma)
    return __builtin_elementwise_fma(a, b, c);
#else
    float2v r; r.x = __builtin_fmaf(a.x, b.x, c.x); r.y = __builtin_fmaf(a.y, b.y, c.y); return r;
#endif
}
// per-block input-dtype detect from x's first 512 ushorts (wave-uniform).
__device__ __forceinline__ int detect_isbf(const unsigned short* xu) {
    int lane = threadIdx.x & 63;
    uint4 v = ((const uint4*)xu)[lane];
    unsigned wv[4] = {v.x, v.y, v.z, v.w};
    bool any = false;
#pragma unroll
    for (int i = 0; i < 4; ++i) {
        any |= (((wv[i] & 0xffffu) >> 7) & 0xffu) >= 160u;
        any |= (((wv[i] >> 16) >> 7) & 0xffu) >= 160u;
    }
    return __popcll(__ballot(any)) < 8;
}

// score-group state: per 16 rows handled by this lane's (r,q) position
struct SGrp {
    float2v a1v, a2v;   // (fsr - M), (ALPHA*fsr - M) broadcast pairs
    float2v s2;         // running sum of unnormalized P
};
__device__ __forceinline__ void sg_init(SGrp& g, float fsr, float maxfd) {
    float Mv = fsr + maxfd;
    float M = fmaxf(Mv, ALPHA * Mv);
    g.a1v.x = fsr - M;         g.a1v.y = g.a1v.x;
    g.a2v.x = ALPHA * fsr - M; g.a2v.y = g.a2v.x;
    g.s2.x = 0.f; g.s2.y = 0.f;
}
// compute 8 scores -> bf16x8 A-fragment; accumulates S into g.s2
__device__ __forceinline__ short8 sg_frag(SGrp& g, const unsigned bw[4],
                                          const float fdx[8]) {
    float2v alv; alv.x = ALPHA; alv.y = ALPHA;
    unsigned dpk[4];
#pragma unroll
    for (int p = 0; p < 4; ++p) {
        float2v fd2; fd2.x = fdx[2 * p]; fd2.y = fdx[2 * p + 1];
        float2v b2;  b2.x = __uint_as_float(bw[p] << 16);
                     b2.y = __uint_as_float(bw[p] & 0xffff0000u);
        float2v t1 = g.a1v + fd2;
        float2v t2 = vfma2(alv, fd2, g.a2v);
        float2v arg = vmax2(t1, t2) + b2;
        float2v pv; pv.x = fexp2(arg.x); pv.y = fexp2(arg.y);
        g.s2 += pv;
        dpk[p] = pk2t(__float_as_uint(pv.x), __float_as_uint(pv.y));
    }
    uintx4 du; du[0] = dpk[0]; du[1] = dpk[1]; du[2] = dpk[2]; du[3] = dpk[3];
    return __builtin_bit_cast(short8, du);
}

// ---------------------------------------------------------------------------
// k01: blocks 0..511: adj -> bf16 additive bias (0 / -inf), 2 MB.
// blocks 512..2559: Wh = x@W, f_src/f_dst via x·(W@a) (log2e-scaled),
// WhB scatter (16x16x32 B-frag). Vectorized dtype-specialized staging.
// ---------------------------------------------------------------------------
__global__ __launch_bounds__(256) void k01_prep_wh(
    const unsigned short* __restrict__ xu, const int* __restrict__ adj,
    const void* __restrict__ x, const void* __restrict__ W,
    const void* __restrict__ a_src, const void* __restrict__ a_dst,
    unsigned short* __restrict__ bias,
    short* __restrict__ WhB, float* __restrict__ f_src, float* __restrict__ f_dst)
{
    int tid = threadIdx.x;
    if (blockIdx.x < 512) {
        int gid = blockIdx.x * 256 + tid;
        long base = (long)gid * 8;
        int4 a0 = *(const int4*)(adj + base);
        int4 a1 = *(const int4*)(adj + base + 4);
        uint4 wv;
        wv.x = (a0.x ? 0u : 0xFF80u) | (a0.y ? 0u : 0xFF800000u);
        wv.y = (a0.z ? 0u : 0xFF80u) | (a0.w ? 0u : 0xFF800000u);
        wv.z = (a1.x ? 0u : 0xFF80u) | (a1.y ? 0u : 0xFF800000u);
        wv.w = (a1.z ? 0u : 0xFF80u) | (a1.w ? 0u : 0xFF800000u);
        *(uint4*)(bias + base) = wv;
        return;
    }
    int isbf = detect_isbf(xu);
    __shared__ float Ws[16][32];
    __shared__ float xs[32][17];
    __shared__ float as_s[32], ad_s[32];
    __shared__ float Wa_s[16], Wad_s[16];
    int bid = blockIdx.x - 512;
    int bh = bid >> 5;            // 0..63
    int n0 = (bid & 31) * 32;
    int b  = bh >> 2, hh = bh & 3;

    if (!isbf) {
        const float* Wf = (const float*)W + hh * 512;
        if (tid < 128) {
            float4 v = *(const float4*)(Wf + tid * 4);
            int f = (tid * 4) >> 5, k = (tid * 4) & 31;
            Ws[f][k] = v.x; Ws[f][k+1] = v.y; Ws[f][k+2] = v.z; Ws[f][k+3] = v.w;
        }
        const float* xf = (const float*)x + ((long)(b * N_ + n0)) * 16;
        if (tid < 128) {
            float4 v = *(const float4*)(xf + tid * 4);
            int r = tid >> 2, f = (tid & 3) * 4;
            xs[r][f] = v.x; xs[r][f+1] = v.y; xs[r][f+2] = v.z; xs[r][f+3] = v.w;
        }
    } else {
        const unsigned short* Wb = (const unsigned short*)W + hh * 512;
        if (tid < 128) {
            ushort4v v = *(const ushort4v*)(Wb + tid * 4);
            int f = (tid * 4) >> 5, k = (tid * 4) & 31;
            Ws[f][k] = bs2f(v[0]); Ws[f][k+1] = bs2f(v[1]);
            Ws[f][k+2] = bs2f(v[2]); Ws[f][k+3] = bs2f(v[3]);
        }
        const unsigned short* xb = (const unsigned short*)x + ((long)(b * N_ + n0)) * 16;
        if (tid < 64) {
            ushort8v v = *(const ushort8v*)(xb + tid * 8);
            int r = tid >> 1, f = (tid & 1) * 8;
#pragma unroll
            for (int i = 0; i < 8; ++i) xs[r][f + i] = bs2f(v[i]);
        }
    }
    if (tid < 32) {
        as_s[tid] = ldin(a_src, hh * 32 + tid, isbf);
        ad_s[tid] = ldin(a_dst, hh * 32 + tid, isbf);
    }
    __syncthreads();

    if (tid < 32) {                       // Wa = W@a
        int f = tid & 15;
        const float* av = (tid < 16) ? as_s : ad_s;
        float s = 0.f;
#pragma unroll
        for (int kk = 0; kk < 32; ++kk) s += Ws[f][kk] * av[kk];
        ((tid < 16) ? Wa_s : Wad_s)[f] = s;
    }
    __syncthreads();

    if (tid < 32) {                       // f_src[n] = x[n]·Wa
        float fs = 0.f, fd = 0.f;
#pragma unroll
        for (int f = 0; f < 16; ++f) {
            fs += xs[tid][f] * Wa_s[f];
            fd += xs[tid][f] * Wad_s[f];
        }
        int n = n0 + tid;
        f_src[bh * N_ + n] = fs * LOG2E;
        f_dst[bh * N_ + n] = fd * LOG2E;
    }

    int k = tid & 31, rb = tid >> 5;
#pragma unroll
    for (int it = 0; it < 4; ++it) {
        int r = it * 8 + rb;
        float acc = 0.f;
#pragma unroll
        for (int f = 0; f < 16; ++f) acc += xs[r][f] * Ws[f][k];
        int n = n0 + r;
        int kstep = n >> 5, quad = (n >> 3) & 3, jj = n & 7;
        int t = k >> 4, l = quad * 16 + (k & 15);
        WhB[((((size_t)bh * 32 + kstep) * 2 + t) * 64 + l) * 8 + jj] = f2bs(acc);
    }
}

// ---------------------------------------------------------------------------
// k2: layer-1 attention, 64 ROWS PER WAVE (4 A-fragments per B-fragment):
// the 2 B-loads + 2 fd-loads per kk serve 4 score groups + 8 MFMAs ->
// WhB/fd traffic per row quarters (vs R13), 4 independent exp chains of ILP.
// 256-row blocks, grid 256 (bh = bid>>2, tile = bid&3).
// ---------------------------------------------------------------------------
__global__ __launch_bounds__(256) void k2_attn1(
    const float* __restrict__ f_src, const float* __restrict__ f_dst,
    const unsigned short* __restrict__ bias, const short* __restrict__ WhB,
    unsigned short* __restrict__ h2)
{
    __shared__ float fdst_s[N_];
    __shared__ float wmax[4];
    __shared__ float Sh[4][64];
    int bid = blockIdx.x;
    int tile = bid & 3;               // 256-row bias slice
    int bh = bid >> 2;                // 0..63
    int tid = threadIdx.x;
    int w = tid >> 6, lane = tid & 63;

    float lmax = -INFINITY;
    for (int idx = tid; idx < N_; idx += 256) {
        float v = f_dst[bh * N_ + idx];
        fdst_s[idx] = v;
        lmax = fmaxf(lmax, v);
    }
#pragma unroll
    for (int m = 32; m; m >>= 1) lmax = fmaxf(lmax, __shfl_xor(lmax, m, 64));
    if (lane == 0) wmax[w] = lmax;
    __syncthreads();
    float maxfd = fmaxf(fmaxf(wmax[0], wmax[1]), fmaxf(wmax[2], wmax[3]));

    int i0 = tile * 256 + w * 64;     // this wave: rows i0..i0+63
    int r = lane & 15, q = lane >> 4;

    SGrp g[4];
#pragma unroll
    for (int gi = 0; gi < 4; ++gi)
        sg_init(g[gi], f_src[bh * N_ + i0 + gi * 16 + r], maxfd);

    floatx4 acc0[4] = {}, acc1[4] = {};
    const unsigned short* brow0 = bias + (size_t)(i0 + r) * N_ + q * 8;
    const float* fdp = fdst_s + q * 8;
    const short* wb = WhB + (((size_t)bh * 64) * 64 + lane) * 8;  // kk stride 1024

    uint4 bu_n[4];
#pragma unroll
    for (int gi = 0; gi < 4; ++gi)
        bu_n[gi] = *(const uint4*)(brow0 + (size_t)(gi * 16) * N_);
    short8 w0_n = *(const short8*)(wb);
    short8 w1_n = *(const short8*)(wb + 512);

#pragma unroll 2
    for (int kk = 0; kk < 32; ++kk) {
        uint4 bu[4];
#pragma unroll
        for (int gi = 0; gi < 4; ++gi) bu[gi] = bu_n[gi];
        short8 bfr0 = w0_n, bfr1 = w1_n;
        if (kk < 31) {
#pragma unroll
            for (int gi = 0; gi < 4; ++gi)
                bu_n[gi] = *(const uint4*)(brow0 + (size_t)(gi * 16) * N_ + (kk + 1) * 32);
            w0_n = *(const short8*)(wb + (kk + 1) * 1024);
            w1_n = *(const short8*)(wb + (kk + 1) * 1024 + 512);
        }
        float4 fda = *(const float4*)(fdp + kk * 32);
        float4 fdb = *(const float4*)(fdp + kk * 32 + 4);
        float fdx[8] = {fda.x, fda.y, fda.z, fda.w, fdb.x, fdb.y, fdb.z, fdb.w};
#pragma unroll
        for (int gi = 0; gi < 4; ++gi) {
            unsigned bw[4] = {bu[gi].x, bu[gi].y, bu[gi].z, bu[gi].w};
            short8 afr = sg_frag(g[gi], bw, fdx);
            acc0[gi] = __builtin_amdgcn_mfma_f32_16x16x32_bf16(afr, bfr0, acc0[gi], 0, 0, 0);
            acc1[gi] = __builtin_amdgcn_mfma_f32_16x16x32_bf16(afr, bfr1, acc1[gi], 0, 0, 0);
        }
    }

#pragma unroll
    for (int gi = 0; gi < 4; ++gi) {
        float s = g[gi].s2.x + g[gi].s2.y;
        s += __shfl_xor(s, 16, 64);
        s += __shfl_xor(s, 32, 64);
        if (lane < 16) Sh[w][gi * 16 + lane] = s;
    }
    __builtin_amdgcn_wave_barrier();   // wave-private LDS ordering

    int bb = bh >> 2, head = bh & 3;
#pragma unroll
    for (int gi = 0; gi < 4; ++gi) {
#pragma unroll
        for (int reg = 0; reg < 4; ++reg) {
            int row = q * 4 + reg;
            float rsv = 1.f / Sh[w][gi * 16 + row];
            unsigned short* hrow =
                &h2[((size_t)(bb * N_ + i0 + gi * 16 + row)) * 128 + head * 32];
            float v0 = acc0[gi][reg] * rsv;
            v0 = v0 > 0.f ? v0 : expm1f(v0);
            hrow[r]      = (unsigned short)f2bs(v0);
            float v1 = acc1[gi][reg] * rsv;
            v1 = v1 > 0.f ? v1 : expm1f(v1);
            hrow[16 + r] = (unsigned short)f2bs(v1);
        }
    }
}

// ---------------------------------------------------------------------------
// k3: Wh2 = h2(bf16) @ W_out (transposed WoT; col15 = ones), g_src/g_dst
// (log2e-scaled), Wh2B scatter. Vectorized staging. grid 1024 x 256.
// ---------------------------------------------------------------------------
__global__ __launch_bounds__(256) void k3_out_proj(
    const unsigned short* __restrict__ xu,
    const unsigned short* __restrict__ h2, const void* __restrict__ W_out,
    const void* __restrict__ a_out_src, const void* __restrict__ a_out_dst,
    short* __restrict__ Wh2B, float* __restrict__ g_src, float* __restrict__ g_dst)
{
    int isbf = detect_isbf(xu);
    __shared__ float WoT[16][132];
    __shared__ float hs[16][132];
    __shared__ float aos[16], aod[16];
    int bid = blockIdx.x;
    int b = bid >> 6;
    int n0 = (bid & 63) * 16;
    int tid = threadIdx.x;

    if (!isbf) {
        const float* Wf = (const float*)W_out;
        for (int idx = tid; idx < 384; idx += 256) {
            float4 v = *(const float4*)(Wf + idx * 4);
            float vv[4] = {v.x, v.y, v.z, v.w};
#pragma unroll
            for (int i = 0; i < 4; ++i) {
                int e = idx * 4 + i;
                WoT[e % NPRED_][e / NPRED_] = vv[i];
            }
        }
    } else {
        const unsigned short* Wb = (const unsigned short*)W_out;
        for (int idx = tid; idx < 192; idx += 256) {
            ushort8v v = *(const ushort8v*)(Wb + idx * 8);
#pragma unroll
            for (int i = 0; i < 8; ++i) {
                int e = idx * 8 + i;
                WoT[e % NPRED_][e / NPRED_] = bs2f(v[i]);
            }
        }
    }
    if (tid < 128) {
#pragma unroll
        for (int p = NPRED_; p < 16; ++p) WoT[p][tid] = 0.f;
    }
    if (tid < 16) {
        aos[tid] = (tid < NPRED_) ? ldin(a_out_src, tid, isbf) : 0.f;
        aod[tid] = (tid < NPRED_) ? ldin(a_out_dst, tid, isbf) : 0.f;
    }
    {
        ushort8v v = *(const ushort8v*)(h2 + ((size_t)(b * N_ + n0 + (tid >> 4))) * 128 + (tid & 15) * 8);
        int r = tid >> 4, c8 = (tid & 15) * 8;
#pragma unroll
        for (int i = 0; i < 8; ++i) hs[r][c8 + i] = bs2f(v[i]);
    }
    __syncthreads();

    int r = tid >> 4, p = tid & 15;
    float acc = 0.f;
#pragma unroll 8
    for (int c4 = 0; c4 < 128; c4 += 4) {
        float4 hv = *(const float4*)&hs[r][c4];
        float4 wv = *(const float4*)&WoT[p][c4];
        acc += hv.x * wv.x + hv.y * wv.y + hv.z * wv.z + hv.w * wv.w;
    }

    float t1 = acc * aos[p], t2 = acc * aod[p];
#pragma unroll
    for (int m = 8; m; m >>= 1) {
        t1 += __shfl_xor(t1, m, 64);
        t2 += __shfl_xor(t2, m, 64);
    }
    int n = n0 + r;
    if (p == 0) {
        g_src[b * N_ + n] = t1 * LOG2E;
        g_dst[b * N_ + n] = t2 * LOG2E;
    }
    int kstep = n >> 5, quad = (n >> 3) & 3, jj = n & 7;
    short val = (p == 15) ? (short)0x3F80 : f2bs(acc);   // ones column -> S
    Wh2B[(((size_t)b * 32 + kstep) * 64 + quad * 16 + p) * 8 + jj] = val;
}

// ---------------------------------------------------------------------------
// k4: layer-2 attention (R10 config), in-register A-frag, S via ones-column,
// bf16 bias, truncate-pack, depth-1 prefetch. XCD swizzle. grid 1024 x 256.
// ---------------------------------------------------------------------------
__global__ __launch_bounds__(256) void k4_attn2(
    const unsigned short* __restrict__ xu,
    const float* __restrict__ g_src, const float* __restrict__ g_dst,
    const unsigned short* __restrict__ bias, const short* __restrict__ Wh2B,
    void* __restrict__ out)
{
    int isbf = detect_isbf(xu);
    __shared__ float gdst_s[N_];
    __shared__ float wmax[4];
    __shared__ float xch[3][64][4];
    int bid = blockIdx.x;
    int xcd = bid & 7, j = bid >> 3;
    int b = j & 15;
    int tile = xcd + 8 * (j >> 4);     // 0..63; tile%8 == xcd
    int tid = threadIdx.x;
    int ch = tid >> 6, lane = tid & 63;

    float lmax = -INFINITY;
    for (int idx = tid; idx < N_; idx += 256) {
        float v = g_dst[b * N_ + idx];
        gdst_s[idx] = v;
        lmax = fmaxf(lmax, v);
    }
#pragma unroll
    for (int m = 32; m; m >>= 1) lmax = fmaxf(lmax, __shfl_xor(lmax, m, 64));
    if (lane == 0) wmax[ch] = lmax;
    __syncthreads();
    float maxgd = fmaxf(fmaxf(wmax[0], wmax[1]), fmaxf(wmax[2], wmax[3]));

    int i0 = tile * 16;
    int r = lane & 15, q = lane >> 4;

    float gsr = g_src[b * N_ + i0 + r];
    float Mv = gsr + maxgd;
    float M = fmaxf(Mv, ALPHA * Mv);
    float2v a1v; a1v.x = gsr - M;          a1v.y = a1v.x;
    float2v a2v; a2v.x = ALPHA * gsr - M;  a2v.y = a2v.x;
    float2v alv; alv.x = ALPHA;            alv.y = ALPHA;

    floatx4 acc = {};
    const unsigned short* brow = bias + (size_t)(i0 + r) * N_ + ch * 256 + q * 8;
    const float* fdp = gdst_s + ch * 256 + q * 8;
    const short* wb = Wh2B + (((size_t)b * 32 + ch * 8) * 64 + lane) * 8;

    uint4  bu_n = *(const uint4*)(brow);
    short8 wf_n = *(const short8*)(wb);

#pragma unroll 4
    for (int kk = 0; kk < 8; ++kk) {
        uint4 bu = bu_n;
        short8 bfr = wf_n;
        if (kk < 7) {
            bu_n = *(const uint4*)(brow + (kk + 1) * 32);
            wf_n = *(const short8*)(wb + (kk + 1) * 512);
        }
        float4 fda = *(const float4*)(fdp + kk * 32);
        float4 fdb = *(const float4*)(fdp + kk * 32 + 4);
        unsigned bw[4] = {bu.x, bu.y, bu.z, bu.w};
        float fdx[8] = {fda.x, fda.y, fda.z, fda.w, fdb.x, fdb.y, fdb.z, fdb.w};
        unsigned dpk[4];
#pragma unroll
        for (int p = 0; p < 4; ++p) {
            float2v fd2; fd2.x = fdx[2 * p]; fd2.y = fdx[2 * p + 1];
            float2v b2;  b2.x = __uint_as_float(bw[p] << 16);
                         b2.y = __uint_as_float(bw[p] & 0xffff0000u);
            float2v t1 = a1v + fd2;
            float2v t2 = vfma2(alv, fd2, a2v);
            float2v arg = vmax2(t1, t2) + b2;
            float2v pv; pv.x = fexp2(arg.x); pv.y = fexp2(arg.y);
            dpk[p] = pk2t(__float_as_uint(pv.x), __float_as_uint(pv.y));
        }
        uintx4 du; du[0] = dpk[0]; du[1] = dpk[1]; du[2] = dpk[2]; du[3] = dpk[3];
        short8 afr = __builtin_bit_cast(short8, du);
        acc = __builtin_amdgcn_mfma_f32_16x16x32_bf16(afr, bfr, acc, 0, 0, 0);
    }

    if (ch != 0) {
#pragma unroll
        for (int i = 0; i < 4; ++i) xch[ch - 1][lane][i] = acc[i];
    }
    __syncthreads();
    if (ch == 0) {
#pragma unroll
        for (int t = 0; t < 3; ++t)
#pragma unroll
            for (int i = 0; i < 4; ++i) acc[i] += xch[t][lane][i];
        int srclane = (lane & 48) + 15;
#pragma unroll
        for (int reg = 0; reg < 4; ++reg) {
            int row = q * 4 + reg;
            float Srow = __shfl(acc[reg], srclane, 64);
            float v = acc[reg] / Srow;
            float o = v > 0.f ? v : expm1f(v);
            if (r < NPRED_) {
                size_t idx = (size_t)b * (N_ * NPRED_) + (size_t)(i0 + row) * NPRED_ + r;
                if (isbf) ((unsigned short*)out)[idx] = (unsigned short)f2bs(o);
                else      ((float*)out)[idx] = o;
            }
        }
    }
}

// ---------------------------------------------------------------------------
extern "C" void kernel_launch(void* const* d_in, const int* in_sizes, int n_in,
                              void* d_out, int out_size, void* d_ws, size_t ws_size,
                              hipStream_t stream)
{
    (void)in_sizes; (void)n_in; (void)out_size; (void)ws_size;
    const void* x      = d_in[0];
    const int*  adj    = (const int*)d_in[1];
    const void* W      = d_in[2];
    const void* a_src  = d_in[3];
    const void* a_dst  = d_in[4];
    const void* W_out  = d_in[5];
    const void* a_osrc = d_in[6];
    const void* a_odst = d_in[7];
    const unsigned short* xu = (const unsigned short*)x;

    char* ws = (char*)d_ws;
    short* WhB   = (short*)(ws);                                  // 4 MB
    float* f_src = (float*)(ws + (4 << 20));                      // 256 KB
    float* f_dst = (float*)(ws + (4 << 20) + (256 << 10));        // 256 KB
    unsigned short* h2 = (unsigned short*)(ws + (4 << 20) + (512 << 10)); // 4 MB
    short* Wh2B  = (short*)(ws + (12 << 20) + (512 << 10));       // 512 KB
    float* g_src = (float*)(ws + (13 << 20));                     // 64 KB
    float* g_dst = (float*)(ws + (13 << 20) + (64 << 10));        // 64 KB
    unsigned short* bias = (unsigned short*)(ws + (14 << 20));    // 2 MB

    hipLaunchKernelGGL(k01_prep_wh, dim3(2560), dim3(256), 0, stream,
                       xu, adj, x, W, a_src, a_dst, bias, WhB, f_src, f_dst);
    hipLaunchKernelGGL(k2_attn1,    dim3(256),  dim3(256), 0, stream,
                       f_src, f_dst, bias, WhB, h2);
    hipLaunchKernelGGL(k3_out_proj, dim3(1024), dim3(256), 0, stream,
                       xu, h2, W_out, a_osrc, a_odst, Wh2B, g_src, g_dst);
    hipLaunchKernelGGL(k4_attn2,    dim3(1024), dim3(256), 0, stream,
                       xu, g_src, g_dst, bias, Wh2B, d_out);
}

// Round 16
// 116.337 us; speedup vs baseline: 1.0392x; 1.0392x over previous
//
#include <hip/hip_runtime.h>
#include <cmath>

// Problem constants
#define B_    16
#define N_    1024
#define NHID_ 32
#define NHEAD_ 4
#define NPRED_ 12
#define ALPHA 0.2f
#define LOG2E 1.442695041f

typedef __attribute__((ext_vector_type(8)))  short          short8;
typedef __attribute__((ext_vector_type(4)))  float          floatx4;
typedef __attribute__((ext_vector_type(2)))  float          float2v;
typedef __attribute__((ext_vector_type(4)))  unsigned       uintx4;
typedef __attribute__((ext_vector_type(4)))  unsigned short ushort4v;
typedef __attribute__((ext_vector_type(8)))  unsigned short ushort8v;

// bf16 bit-pattern helpers
__device__ __forceinline__ float bs2f(unsigned short s) {
    return __uint_as_float(((unsigned)s) << 16);
}
__device__ __forceinline__ short f2bs(float f) {
    unsigned u = __float_as_uint(f);
    unsigned r = (u + 0x7fffu + ((u >> 16) & 1u)) >> 16;  // RNE
    return (short)r;
}
__device__ __forceinline__ float ldin(const void* p, long i, int isbf) {
    if (isbf) return bs2f(((const unsigned short*)p)[i]);
    return ((const float*)p)[i];
}
__device__ __forceinline__ float fexp2(float x) {
#if __has_builtin(__builtin_amdgcn_exp2f)
    return __builtin_amdgcn_exp2f(x);
#else
    return __expf(x * 0.6931471805599453f);
#endif
}
// pack high halves of two fp32 into bf16x2 (truncation / RTZ)
__device__ __forceinline__ unsigned pk2t(unsigned u0, unsigned u1) {
#if __has_builtin(__builtin_amdgcn_perm)
    return __builtin_amdgcn_perm(u1, u0, 0x07060302u);
#else
    return (u0 >> 16) | (u1 & 0xffff0000u);
#endif
}
__device__ __forceinline__ float2v vmax2(float2v a, float2v b) {
#if __has_builtin(__builtin_elementwise_max)
    return __builtin_elementwise_max(a, b);
#else
    float2v r; r.x = fmaxf(a.x, b.x); r.y = fmaxf(a.y, b.y); return r;
#endif
}
__device__ __forceinline__ float2v vfma2(float2v a, float2v b, float2v c) {
#if __has_builtin(__builtin_elementwise_fma)
    return __builtin_elementwise_fma(a, b, c);
#else
    float2v r; r.x = __builtin_fmaf(a.x, b.x, c.x); r.y = __builtin_fmaf(a.y, b.y, c.y); return r;
#endif
}
// per-block input-dtype detect from x's first 512 ushorts (wave-uniform).
__device__ __forceinline__ int detect_isbf(const unsigned short* xu) {
    int lane = threadIdx.x & 63;
    uint4 v = ((const uint4*)xu)[lane];
    unsigned wv[4] = {v.x, v.y, v.z, v.w};
    bool any = false;
#pragma unroll
    for (int i = 0; i < 4; ++i) {
        any |= (((wv[i] & 0xffffu) >> 7) & 0xffu) >= 160u;
        any |= (((wv[i] >> 16) >> 7) & 0xffu) >= 160u;
    }
    return __popcll(__ballot(any)) < 8;
}

// score-group state: per 16 rows handled by this lane's (r,q) position
struct SGrp {
    float2v a1v, a2v;   // (fsr - M), (ALPHA*fsr - M) broadcast pairs
    float2v s2;         // running sum of unnormalized P
};
__device__ __forceinline__ void sg_init(SGrp& g, float fsr, float maxfd) {
    float Mv = fsr + maxfd;
    float M = fmaxf(Mv, ALPHA * Mv);
    g.a1v.x = fsr - M;         g.a1v.y = g.a1v.x;
    g.a2v.x = ALPHA * fsr - M; g.a2v.y = g.a2v.x;
    g.s2.x = 0.f; g.s2.y = 0.f;
}
// compute 8 scores -> bf16x8 A-fragment; accumulates S into g.s2
__device__ __forceinline__ short8 sg_frag(SGrp& g, const unsigned bw[4],
                                          const float fdx[8]) {
    float2v alv; alv.x = ALPHA; alv.y = ALPHA;
    unsigned dpk[4];
#pragma unroll
    for (int p = 0; p < 4; ++p) {
        float2v fd2; fd2.x = fdx[2 * p]; fd2.y = fdx[2 * p + 1];
        float2v b2;  b2.x = __uint_as_float(bw[p] << 16);
                     b2.y = __uint_as_float(bw[p] & 0xffff0000u);
        float2v t1 = g.a1v + fd2;
        float2v t2 = vfma2(alv, fd2, g.a2v);
        float2v arg = vmax2(t1, t2) + b2;
        float2v pv; pv.x = fexp2(arg.x); pv.y = fexp2(arg.y);
        g.s2 += pv;
        dpk[p] = pk2t(__float_as_uint(pv.x), __float_as_uint(pv.y));
    }
    uintx4 du; du[0] = dpk[0]; du[1] = dpk[1]; du[2] = dpk[2]; du[3] = dpk[3];
    return __builtin_bit_cast(short8, du);
}

// ---------------------------------------------------------------------------
// k01: blocks 0..511: adj -> bf16 additive bias (0 / -inf), 2 MB.
// blocks 512..2559: Wh = x@W, f_src/f_dst via x·(W@a) (log2e-scaled),
// WhB scatter (16x16x32 B-frag). Vectorized dtype-specialized staging.
// ---------------------------------------------------------------------------
__global__ __launch_bounds__(256) void k01_prep_wh(
    const unsigned short* __restrict__ xu, const int* __restrict__ adj,
    const void* __restrict__ x, const void* __restrict__ W,
    const void* __restrict__ a_src, const void* __restrict__ a_dst,
    unsigned short* __restrict__ bias,
    short* __restrict__ WhB, float* __restrict__ f_src, float* __restrict__ f_dst)
{
    int tid = threadIdx.x;
    if (blockIdx.x < 512) {
        int gid = blockIdx.x * 256 + tid;
        long base = (long)gid * 8;
        int4 a0 = *(const int4*)(adj + base);
        int4 a1 = *(const int4*)(adj + base + 4);
        uint4 wv;
        wv.x = (a0.x ? 0u : 0xFF80u) | (a0.y ? 0u : 0xFF800000u);
        wv.y = (a0.z ? 0u : 0xFF80u) | (a0.w ? 0u : 0xFF800000u);
        wv.z = (a1.x ? 0u : 0xFF80u) | (a1.y ? 0u : 0xFF800000u);
        wv.w = (a1.z ? 0u : 0xFF80u) | (a1.w ? 0u : 0xFF800000u);
        *(uint4*)(bias + base) = wv;
        return;
    }
    int isbf = detect_isbf(xu);
    __shared__ float Ws[16][32];
    __shared__ float xs[32][17];
    __shared__ float as_s[32], ad_s[32];
    __shared__ float Wa_s[16], Wad_s[16];
    int bid = blockIdx.x - 512;
    int bh = bid >> 5;            // 0..63
    int n0 = (bid & 31) * 32;
    int b  = bh >> 2, hh = bh & 3;

    if (!isbf) {
        const float* Wf = (const float*)W + hh * 512;
        if (tid < 128) {
            float4 v = *(const float4*)(Wf + tid * 4);
            int f = (tid * 4) >> 5, k = (tid * 4) & 31;
            Ws[f][k] = v.x; Ws[f][k+1] = v.y; Ws[f][k+2] = v.z; Ws[f][k+3] = v.w;
        }
        const float* xf = (const float*)x + ((long)(b * N_ + n0)) * 16;
        if (tid < 128) {
            float4 v = *(const float4*)(xf + tid * 4);
            int r = tid >> 2, f = (tid & 3) * 4;
            xs[r][f] = v.x; xs[r][f+1] = v.y; xs[r][f+2] = v.z; xs[r][f+3] = v.w;
        }
    } else {
        const unsigned short* Wb = (const unsigned short*)W + hh * 512;
        if (tid < 128) {
            ushort4v v = *(const ushort4v*)(Wb + tid * 4);
            int f = (tid * 4) >> 5, k = (tid * 4) & 31;
            Ws[f][k] = bs2f(v[0]); Ws[f][k+1] = bs2f(v[1]);
            Ws[f][k+2] = bs2f(v[2]); Ws[f][k+3] = bs2f(v[3]);
        }
        const unsigned short* xb = (const unsigned short*)x + ((long)(b * N_ + n0)) * 16;
        if (tid < 64) {
            ushort8v v = *(const ushort8v*)(xb + tid * 8);
            int r = tid >> 1, f = (tid & 1) * 8;
#pragma unroll
            for (int i = 0; i < 8; ++i) xs[r][f + i] = bs2f(v[i]);
        }
    }
    if (tid < 32) {
        as_s[tid] = ldin(a_src, hh * 32 + tid, isbf);
        ad_s[tid] = ldin(a_dst, hh * 32 + tid, isbf);
    }
    __syncthreads();

    if (tid < 32) {                       // Wa = W@a
        int f = tid & 15;
        const float* av = (tid < 16) ? as_s : ad_s;
        float s = 0.f;
#pragma unroll
        for (int kk = 0; kk < 32; ++kk) s += Ws[f][kk] * av[kk];
        ((tid < 16) ? Wa_s : Wad_s)[f] = s;
    }
    __syncthreads();

    if (tid < 32) {                       // f_src[n] = x[n]·Wa
        float fs = 0.f, fd = 0.f;
#pragma unroll
        for (int f = 0; f < 16; ++f) {
            fs += xs[tid][f] * Wa_s[f];
            fd += xs[tid][f] * Wad_s[f];
        }
        int n = n0 + tid;
        f_src[bh * N_ + n] = fs * LOG2E;
        f_dst[bh * N_ + n] = fd * LOG2E;
    }

    int k = tid & 31, rb = tid >> 5;
#pragma unroll
    for (int it = 0; it < 4; ++it) {
        int r = it * 8 + rb;
        float acc = 0.f;
#pragma unroll
        for (int f = 0; f < 16; ++f) acc += xs[r][f] * Ws[f][k];
        int n = n0 + r;
        int kstep = n >> 5, quad = (n >> 3) & 3, jj = n & 7;
        int t = k >> 4, l = quad * 16 + (k & 15);
        WhB[((((size_t)bh * 32 + kstep) * 2 + t) * 64 + l) * 8 + jj] = f2bs(acc);
    }
}

// ---------------------------------------------------------------------------
// k2: layer-1 attention, 32 ROWS PER WAVE (2 A-fragments per B-fragment) —
// R14 config (best measured). 128-row blocks, grid 512.
// ---------------------------------------------------------------------------
__global__ __launch_bounds__(256) void k2_attn1(
    const float* __restrict__ f_src, const float* __restrict__ f_dst,
    const unsigned short* __restrict__ bias, const short* __restrict__ WhB,
    unsigned short* __restrict__ h2)
{
    __shared__ float fdst_s[N_];
    __shared__ float wmax[4];
    __shared__ float Sh[4][32];
    int bid = blockIdx.x;
    int tile = bid & 7;               // == XCD slot; 128-row bias slice
    int bh = bid >> 3;                // 0..63
    int tid = threadIdx.x;
    int w = tid >> 6, lane = tid & 63;

    float lmax = -INFINITY;
    for (int idx = tid; idx < N_; idx += 256) {
        float v = f_dst[bh * N_ + idx];
        fdst_s[idx] = v;
        lmax = fmaxf(lmax, v);
    }
#pragma unroll
    for (int m = 32; m; m >>= 1) lmax = fmaxf(lmax, __shfl_xor(lmax, m, 64));
    if (lane == 0) wmax[w] = lmax;
    __syncthreads();
    float maxfd = fmaxf(fmaxf(wmax[0], wmax[1]), fmaxf(wmax[2], wmax[3]));

    int i0 = tile * 128 + w * 32;     // this wave: rows i0..i0+31
    int r = lane & 15, q = lane >> 4;

    SGrp gA, gB;
    sg_init(gA, f_src[bh * N_ + i0 + r],      maxfd);
    sg_init(gB, f_src[bh * N_ + i0 + 16 + r], maxfd);

    floatx4 acc0A = {}, acc1A = {}, acc0B = {}, acc1B = {};
    const unsigned short* browA = bias + (size_t)(i0 + r) * N_ + q * 8;
    const unsigned short* browB = browA + (size_t)16 * N_;
    const float* fdp = fdst_s + q * 8;
    const short* wb = WhB + (((size_t)bh * 64) * 64 + lane) * 8;  // kk stride 1024

    uint4  buA_n = *(const uint4*)(browA);
    uint4  buB_n = *(const uint4*)(browB);
    short8 w0_n = *(const short8*)(wb);
    short8 w1_n = *(const short8*)(wb + 512);

#pragma unroll 2
    for (int kk = 0; kk < 32; ++kk) {
        uint4 buA = buA_n, buB = buB_n;
        short8 bfr0 = w0_n, bfr1 = w1_n;
        if (kk < 31) {
            buA_n = *(const uint4*)(browA + (kk + 1) * 32);
            buB_n = *(const uint4*)(browB + (kk + 1) * 32);
            w0_n = *(const short8*)(wb + (kk + 1) * 1024);
            w1_n = *(const short8*)(wb + (kk + 1) * 1024 + 512);
        }
        float4 fda = *(const float4*)(fdp + kk * 32);
        float4 fdb = *(const float4*)(fdp + kk * 32 + 4);
        float fdx[8] = {fda.x, fda.y, fda.z, fda.w, fdb.x, fdb.y, fdb.z, fdb.w};
        unsigned bwA[4] = {buA.x, buA.y, buA.z, buA.w};
        unsigned bwB[4] = {buB.x, buB.y, buB.z, buB.w};
        short8 afrA = sg_frag(gA, bwA, fdx);
        short8 afrB = sg_frag(gB, bwB, fdx);
        acc0A = __builtin_amdgcn_mfma_f32_16x16x32_bf16(afrA, bfr0, acc0A, 0, 0, 0);
        acc1A = __builtin_amdgcn_mfma_f32_16x16x32_bf16(afrA, bfr1, acc1A, 0, 0, 0);
        acc0B = __builtin_amdgcn_mfma_f32_16x16x32_bf16(afrB, bfr0, acc0B, 0, 0, 0);
        acc1B = __builtin_amdgcn_mfma_f32_16x16x32_bf16(afrB, bfr1, acc1B, 0, 0, 0);
    }

    float sA = gA.s2.x + gA.s2.y;
    sA += __shfl_xor(sA, 16, 64);
    sA += __shfl_xor(sA, 32, 64);
    float sB = gB.s2.x + gB.s2.y;
    sB += __shfl_xor(sB, 16, 64);
    sB += __shfl_xor(sB, 32, 64);
    if (lane < 16) { Sh[w][lane] = sA; Sh[w][16 + lane] = sB; }
    __builtin_amdgcn_wave_barrier();   // wave-private LDS ordering

    int bb = bh >> 2, head = bh & 3;
#pragma unroll
    for (int reg = 0; reg < 4; ++reg) {
        int row = q * 4 + reg;
        {   // group A: rows i0..i0+15
            float rsv = 1.f / Sh[w][row];
            unsigned short* hrow = &h2[((size_t)(bb * N_ + i0 + row)) * 128 + head * 32];
            float v0 = acc0A[reg] * rsv;
            v0 = v0 > 0.f ? v0 : expm1f(v0);
            hrow[r]      = (unsigned short)f2bs(v0);
            float v1 = acc1A[reg] * rsv;
            v1 = v1 > 0.f ? v1 : expm1f(v1);
            hrow[16 + r] = (unsigned short)f2bs(v1);
        }
        {   // group B: rows i0+16..i0+31
            float rsv = 1.f / Sh[w][16 + row];
            unsigned short* hrow = &h2[((size_t)(bb * N_ + i0 + 16 + row)) * 128 + head * 32];
            float v0 = acc0B[reg] * rsv;
            v0 = v0 > 0.f ? v0 : expm1f(v0);
            hrow[r]      = (unsigned short)f2bs(v0);
            float v1 = acc1B[reg] * rsv;
            v1 = v1 > 0.f ? v1 : expm1f(v1);
            hrow[16 + r] = (unsigned short)f2bs(v1);
        }
    }
}

// ---------------------------------------------------------------------------
// k3: Wh2 = h2(bf16) @ W_out (transposed WoT; col15 = ones), g_src/g_dst
// (log2e-scaled), Wh2B scatter. Vectorized staging. grid 1024 x 256.
// ---------------------------------------------------------------------------
__global__ __launch_bounds__(256) void k3_out_proj(
    const unsigned short* __restrict__ xu,
    const unsigned short* __restrict__ h2, const void* __restrict__ W_out,
    const void* __restrict__ a_out_src, const void* __restrict__ a_out_dst,
    short* __restrict__ Wh2B, float* __restrict__ g_src, float* __restrict__ g_dst)
{
    int isbf = detect_isbf(xu);
    __shared__ float WoT[16][132];
    __shared__ float hs[16][132];
    __shared__ float aos[16], aod[16];
    int bid = blockIdx.x;
    int b = bid >> 6;
    int n0 = (bid & 63) * 16;
    int tid = threadIdx.x;

    if (!isbf) {
        const float* Wf = (const float*)W_out;
        for (int idx = tid; idx < 384; idx += 256) {
            float4 v = *(const float4*)(Wf + idx * 4);
            float vv[4] = {v.x, v.y, v.z, v.w};
#pragma unroll
            for (int i = 0; i < 4; ++i) {
                int e = idx * 4 + i;
                WoT[e % NPRED_][e / NPRED_] = vv[i];
            }
        }
    } else {
        const unsigned short* Wb = (const unsigned short*)W_out;
        for (int idx = tid; idx < 192; idx += 256) {
            ushort8v v = *(const ushort8v*)(Wb + idx * 8);
#pragma unroll
            for (int i = 0; i < 8; ++i) {
                int e = idx * 8 + i;
                WoT[e % NPRED_][e / NPRED_] = bs2f(v[i]);
            }
        }
    }
    if (tid < 128) {
#pragma unroll
        for (int p = NPRED_; p < 16; ++p) WoT[p][tid] = 0.f;
    }
    if (tid < 16) {
        aos[tid] = (tid < NPRED_) ? ldin(a_out_src, tid, isbf) : 0.f;
        aod[tid] = (tid < NPRED_) ? ldin(a_out_dst, tid, isbf) : 0.f;
    }
    {
        ushort8v v = *(const ushort8v*)(h2 + ((size_t)(b * N_ + n0 + (tid >> 4))) * 128 + (tid & 15) * 8);
        int r = tid >> 4, c8 = (tid & 15) * 8;
#pragma unroll
        for (int i = 0; i < 8; ++i) hs[r][c8 + i] = bs2f(v[i]);
    }
    __syncthreads();

    int r = tid >> 4, p = tid & 15;
    float acc = 0.f;
#pragma unroll 8
    for (int c4 = 0; c4 < 128; c4 += 4) {
        float4 hv = *(const float4*)&hs[r][c4];
        float4 wv = *(const float4*)&WoT[p][c4];
        acc += hv.x * wv.x + hv.y * wv.y + hv.z * wv.z + hv.w * wv.w;
    }

    float t1 = acc * aos[p], t2 = acc * aod[p];
#pragma unroll
    for (int m = 8; m; m >>= 1) {
        t1 += __shfl_xor(t1, m, 64);
        t2 += __shfl_xor(t2, m, 64);
    }
    int n = n0 + r;
    if (p == 0) {
        g_src[b * N_ + n] = t1 * LOG2E;
        g_dst[b * N_ + n] = t2 * LOG2E;
    }
    int kstep = n >> 5, quad = (n >> 3) & 3, jj = n & 7;
    short val = (p == 15) ? (short)0x3F80 : f2bs(acc);   // ones column -> S
    Wh2B[(((size_t)b * 32 + kstep) * 64 + quad * 16 + p) * 8 + jj] = val;
}

// ---------------------------------------------------------------------------
// k4: layer-2 attention, 32 ROWS PER BLOCK (2 A-groups per Wh2B-load, R14's
// proven reuse pattern): each ch-wave owns 8 kk x 2 row-groups -> Wh2B/gdst
// traffic per row halves, exp ILP doubles. S via ones-column per group.
// XCD swizzle. grid 512 x 256.
// ---------------------------------------------------------------------------
__global__ __launch_bounds__(256) void k4_attn2(
    const unsigned short* __restrict__ xu,
    const float* __restrict__ g_src, const float* __restrict__ g_dst,
    const unsigned short* __restrict__ bias, const short* __restrict__ Wh2B,
    void* __restrict__ out)
{
    int isbf = detect_isbf(xu);
    __shared__ float gdst_s[N_];
    __shared__ float wmax[4];
    __shared__ float xch[3][64][8];
    int bid = blockIdx.x;
    int xcd = bid & 7, j = bid >> 3;
    int b = j & 15;
    int T = xcd + 8 * (j >> 4);        // 0..31; T%8 == xcd
    int tid = threadIdx.x;
    int ch = tid >> 6, lane = tid & 63;
    int i0 = T * 32;                   // rows i0..i0+31

    float lmax = -INFINITY;
    for (int idx = tid; idx < N_; idx += 256) {
        float v = g_dst[b * N_ + idx];
        gdst_s[idx] = v;
        lmax = fmaxf(lmax, v);
    }
#pragma unroll
    for (int m = 32; m; m >>= 1) lmax = fmaxf(lmax, __shfl_xor(lmax, m, 64));
    if (lane == 0) wmax[ch] = lmax;
    __syncthreads();
    float maxgd = fmaxf(fmaxf(wmax[0], wmax[1]), fmaxf(wmax[2], wmax[3]));

    int r = lane & 15, q = lane >> 4;

    SGrp gA, gB;
    sg_init(gA, g_src[b * N_ + i0 + r],      maxgd);
    sg_init(gB, g_src[b * N_ + i0 + 16 + r], maxgd);

    floatx4 accA = {}, accB = {};
    const unsigned short* browA = bias + (size_t)(i0 + r) * N_ + ch * 256 + q * 8;
    const unsigned short* browB = browA + (size_t)16 * N_;
    const float* fdp = gdst_s + ch * 256 + q * 8;
    const short* wb = Wh2B + (((size_t)b * 32 + ch * 8) * 64 + lane) * 8;

    uint4  buA_n = *(const uint4*)(browA);
    uint4  buB_n = *(const uint4*)(browB);
    short8 wf_n = *(const short8*)(wb);

#pragma unroll 4
    for (int kk = 0; kk < 8; ++kk) {
        uint4 buA = buA_n, buB = buB_n;
        short8 bfr = wf_n;
        if (kk < 7) {
            buA_n = *(const uint4*)(browA + (kk + 1) * 32);
            buB_n = *(const uint4*)(browB + (kk + 1) * 32);
            wf_n = *(const short8*)(wb + (kk + 1) * 512);
        }
        float4 fda = *(const float4*)(fdp + kk * 32);
        float4 fdb = *(const float4*)(fdp + kk * 32 + 4);
        float fdx[8] = {fda.x, fda.y, fda.z, fda.w, fdb.x, fdb.y, fdb.z, fdb.w};
        unsigned bwA[4] = {buA.x, buA.y, buA.z, buA.w};
        unsigned bwB[4] = {buB.x, buB.y, buB.z, buB.w};
        short8 afrA = sg_frag(gA, bwA, fdx);
        short8 afrB = sg_frag(gB, bwB, fdx);
        accA = __builtin_amdgcn_mfma_f32_16x16x32_bf16(afrA, bfr, accA, 0, 0, 0);
        accB = __builtin_amdgcn_mfma_f32_16x16x32_bf16(afrB, bfr, accB, 0, 0, 0);
    }

    if (ch != 0) {
#pragma unroll
        for (int i = 0; i < 4; ++i) {
            xch[ch - 1][lane][i]     = accA[i];
            xch[ch - 1][lane][4 + i] = accB[i];
        }
    }
    __syncthreads();
    if (ch == 0) {
#pragma unroll
        for (int t = 0; t < 3; ++t)
#pragma unroll
            for (int i = 0; i < 4; ++i) {
                accA[i] += xch[t][lane][i];
                accB[i] += xch[t][lane][4 + i];
            }
        int srclane = (lane & 48) + 15;
#pragma unroll
        for (int reg = 0; reg < 4; ++reg) {
            int row = q * 4 + reg;
            {   // group A: rows i0..i0+15
                float Srow = __shfl(accA[reg], srclane, 64);
                float v = accA[reg] / Srow;
                float o = v > 0.f ? v : expm1f(v);
                if (r < NPRED_) {
                    size_t idx = (size_t)b * (N_ * NPRED_) + (size_t)(i0 + row) * NPRED_ + r;
                    if (isbf) ((unsigned short*)out)[idx] = (unsigned short)f2bs(o);
                    else      ((float*)out)[idx] = o;
                }
            }
            {   // group B: rows i0+16..i0+31
                float Srow = __shfl(accB[reg], srclane, 64);
                float v = accB[reg] / Srow;
                float o = v > 0.f ? v : expm1f(v);
                if (r < NPRED_) {
                    size_t idx = (size_t)b * (N_ * NPRED_) + (size_t)(i0 + 16 + row) * NPRED_ + r;
                    if (isbf) ((unsigned short*)out)[idx] = (unsigned short)f2bs(o);
                    else      ((float*)out)[idx] = o;
                }
            }
        }
    }
}

// ---------------------------------------------------------------------------
extern "C" void kernel_launch(void* const* d_in, const int* in_sizes, int n_in,
                              void* d_out, int out_size, void* d_ws, size_t ws_size,
                              hipStream_t stream)
{
    (void)in_sizes; (void)n_in; (void)out_size; (void)ws_size;
    const void* x      = d_in[0];
    const int*  adj    = (const int*)d_in[1];
    const void* W      = d_in[2];
    const void* a_src  = d_in[3];
    const void* a_dst  = d_in[4];
    const void* W_out  = d_in[5];
    const void* a_osrc = d_in[6];
    const void* a_odst = d_in[7];
    const unsigned short* xu = (const unsigned short*)x;

    char* ws = (char*)d_ws;
    short* WhB   = (short*)(ws);                                  // 4 MB
    float* f_src = (float*)(ws + (4 << 20));                      // 256 KB
    float* f_dst = (float*)(ws + (4 << 20) + (256 << 10));        // 256 KB
    unsigned short* h2 = (unsigned short*)(ws + (4 << 20) + (512 << 10)); // 4 MB
    short* Wh2B  = (short*)(ws + (12 << 20) + (512 << 10));       // 512 KB
    float* g_src = (float*)(ws + (13 << 20));                     // 64 KB
    float* g_dst = (float*)(ws + (13 << 20) + (64 << 10));        // 64 KB
    unsigned short* bias = (unsigned short*)(ws + (14 << 20));    // 2 MB

    hipLaunchKernelGGL(k01_prep_wh, dim3(2560), dim3(256), 0, stream,
                       xu, adj, x, W, a_src, a_dst, bias, WhB, f_src, f_dst);
    hipLaunchKernelGGL(k2_attn1,    dim3(512),  dim3(256), 0, stream,
                       f_src, f_dst, bias, WhB, h2);
    hipLaunchKernelGGL(k3_out_proj, dim3(1024), dim3(256), 0, stream,
                       xu, h2, W_out, a_osrc, a_odst, Wh2B, g_src, g_dst);
    hipLaunchKernelGGL(k4_attn2,    dim3(512),  dim3(256), 0, stream,
                       xu, g_src, g_dst, bias, Wh2B, d_out);
}